// Round 1
// baseline (305.471 us; speedup 1.0000x reference)
//
#include <hip/hip_runtime.h>
#include <math.h>

#define BATCH 8
#define CH    256
#define NPIX  4096
#define CKDIM 64

typedef __attribute__((ext_vector_type(8))) short short8;   // 8 bf16 (4 VGPRs)
typedef __attribute__((ext_vector_type(4))) float f32x4;    // MFMA accumulator

#define MFMA16x16(a, b, c) __builtin_amdgcn_mfma_f32_16x16x32_bf16((a), (b), (c), 0, 0, 0)

__device__ __forceinline__ unsigned short f2bf(float f) {
    union { float f; unsigned int u; } v; v.f = f;
    unsigned int u = v.u;
    u += 0x7fffu + ((u >> 16) & 1u);      // round-to-nearest-even
    return (unsigned short)(u >> 16);
}

// ---------------------------------------------------------------------------
// Kernel P: build W_all[384][256] bf16 (rows: 0-63 wq, 64-127 wk, 128-383 wg@wv)
// and bias_all[384] fp32. grid 384 x 256 threads.
// ---------------------------------------------------------------------------
__global__ void prep_kernel(const float* __restrict__ wq, const float* __restrict__ bq,
                            const float* __restrict__ wk, const float* __restrict__ bk,
                            const float* __restrict__ wv, const float* __restrict__ bv,
                            const float* __restrict__ wg,
                            unsigned short* __restrict__ W_all, float* __restrict__ bias_all) {
    int o = blockIdx.x;
    int c = threadIdx.x;
    if (o < 64) {
        W_all[o * CH + c] = f2bf(wq[o * CH + c]);
        if (c == 0) bias_all[o] = bq[o];
    } else if (o < 128) {
        int oo = o - 64;
        W_all[o * CH + c] = f2bf(wk[oo * CH + c]);
        if (c == 0) bias_all[o] = bk[oo];
    } else {
        int oo = o - 128;
        float acc = 0.f;
        for (int m = 0; m < CH; ++m)
            acc += wg[oo * CH + m] * wv[m * CH + c];
        W_all[o * CH + c] = f2bf(acc);
        if (c == 0) {
            float b = 0.f;
            for (int m = 0; m < CH; ++m) b += wg[oo * CH + m] * bv[m];
            bias_all[o] = b;
        }
    }
}

// ---------------------------------------------------------------------------
// Kernel T: transpose+convert x[b][c][n] fp32 -> xt[b][n][c] bf16.
// 64x64 tiles, 256 threads. LDS stride 65 (<=2-way banks). grid (64, 4, 8).
// ---------------------------------------------------------------------------
__global__ void xpose_kernel(const float* __restrict__ x, unsigned short* __restrict__ xt) {
    __shared__ float Tl[64][65];   // [n][c]
    int n0 = blockIdx.x * 64;
    int c0 = blockIdx.y * 64;
    int b  = blockIdx.z;
    int tid = threadIdx.x;

#pragma unroll
    for (int r = 0; r < 4; ++r) {
        int f  = r * 256 + tid;
        int c  = f >> 4;
        int n4 = f & 15;
        float4 v = *(const float4*)(x + ((size_t)b * CH + c0 + c) * NPIX + n0 + n4 * 4);
        Tl[n4 * 4 + 0][c] = v.x;
        Tl[n4 * 4 + 1][c] = v.y;
        Tl[n4 * 4 + 2][c] = v.z;
        Tl[n4 * 4 + 3][c] = v.w;
    }
    __syncthreads();
#pragma unroll
    for (int r = 0; r < 2; ++r) {
        int f    = r * 256 + tid;
        int nrow = f >> 3;
        int c8   = f & 7;
        unsigned int pk[4];
#pragma unroll
        for (int p = 0; p < 4; ++p) {
            unsigned int lo = f2bf(Tl[nrow][c8 * 8 + p * 2 + 0]);
            unsigned int hi = f2bf(Tl[nrow][c8 * 8 + p * 2 + 1]);
            pk[p] = lo | (hi << 16);
        }
        *(uint4*)(xt + ((size_t)b * NPIX + n0 + nrow) * CH + c0 + c8 * 8) = *(uint4*)pk;
    }
}

// ---------------------------------------------------------------------------
// Kernel G: qkv GEMM. Stage 64n x 256ch xt tile in LDS once; loop 6 o-groups.
// y[o][n] = sum_c W_all[o][c] xt[n][c] + bias. o<128 -> qk[b][n][128];
// o>=128 -> vp[b][o-128][n]. grid (64, 8), 256 threads (4 waves).
// ---------------------------------------------------------------------------
__global__ void qkv_mfma(const unsigned short* __restrict__ xt,
                         const unsigned short* __restrict__ W_all,
                         const float* __restrict__ bias_all,
                         unsigned short* __restrict__ qk, unsigned short* __restrict__ vp) {
    __shared__ __align__(16) unsigned short Xl[64][264];   // 33 KB, stride 264 (~conflict-min)

    int n0   = blockIdx.x * 64;
    int b    = blockIdx.y;
    int tid  = threadIdx.x;
    int lane = tid & 63;
    int w    = tid >> 6;
    int col  = lane & 15;
    int quad = lane >> 4;

    // stage xt tile: 64 rows x 256 ch (8 uint4/thread, coalesced)
#pragma unroll
    for (int r = 0; r < 8; ++r) {
        int f   = r * 256 + tid;
        int row = f >> 5;            // 32 uint4 per row
        int c8  = f & 31;
        *(uint4*)&Xl[row][c8 * 8] = *(const uint4*)(xt + ((size_t)b * NPIX + n0 + row) * CH + c8 * 8);
    }
    __syncthreads();

#pragma unroll
    for (int og = 0; og < 6; ++og) {
        int o0 = og * 64;
        const unsigned short* Arow = W_all + (size_t)(o0 + w * 16 + col) * CH + quad * 8;

        f32x4 acc[4];
#pragma unroll
        for (int t = 0; t < 4; ++t) acc[t] = (f32x4){0.f, 0.f, 0.f, 0.f};

#pragma unroll
        for (int kc = 0; kc < 8; ++kc) {
            short8 a = *(const short8*)(Arow + kc * 32);   // L2-hot (196 KB total W)
#pragma unroll
            for (int nt = 0; nt < 4; ++nt) {
                short8 bb = *(const short8*)&Xl[nt * 16 + col][kc * 32 + quad * 8];
                acc[nt] = MFMA16x16(a, bb, acc[nt]);
            }
        }

        float4 bias = *(const float4*)(bias_all + o0 + w * 16 + quad * 4);
        float bs[4] = {bias.x, bias.y, bias.z, bias.w};

        if (og < 2) {
            // q/k: transposed store qk[b][n][o] (uint2 per tile)
#pragma unroll
            for (int nt = 0; nt < 4; ++nt) {
                int n = n0 + nt * 16 + col;
                unsigned int pk[2];
#pragma unroll
                for (int p = 0; p < 2; ++p) {
                    unsigned int lo = f2bf(acc[nt][p * 2 + 0] + bs[p * 2 + 0]);
                    unsigned int hi = f2bf(acc[nt][p * 2 + 1] + bs[p * 2 + 1]);
                    pk[p] = lo | (hi << 16);
                }
                *(uint2*)(qk + ((size_t)b * NPIX + n) * 128 + o0 + w * 16 + quad * 4) = *(uint2*)pk;
            }
        } else {
#pragma unroll
            for (int nt = 0; nt < 4; ++nt) {
                int n = n0 + nt * 16 + col;
#pragma unroll
                for (int r = 0; r < 4; ++r) {
                    int oo = o0 - 128 + w * 16 + quad * 4 + r;
                    vp[((size_t)b * CH + oo) * NPIX + n] = f2bf(acc[nt][r] + bs[r]);
                }
            }
        }
    }
}

// ---------------------------------------------------------------------------
// Kernel A v5: j-tile 128 per block, grid (32,8)=256 blocks (1/CU), 8 waves.
// Phase B 4x4 register blocking (wave = 64o x 64j, acc 16 x f32x4): LDS reads
// drop to 0.5 b128/MFMA. Phase A: 2i x 2j subtiles per wave, K in registers.
// Double-buffered Q/V LDS + async reg-staging (issue loads at iter top, ds_write
// to other buffer after phase B): staging off the critical path, 2 barriers/iter.
// LDS: Qt 2x9.2 + Vl 2x36.9 + St 18.4 = 108 KB.
// ---------------------------------------------------------------------------
#define LPK 72
__global__ __launch_bounds__(512, 2)
void attn_v5(const unsigned short* __restrict__ qk,   // [B][N][128]: q=0..63, k=64..127
             const unsigned short* __restrict__ vp,   // [B][256][N]
             const float* __restrict__ bg, float* __restrict__ out) {
    __shared__ __align__(16) unsigned short Qt[2][64][LPK];    // [buf][i][ch]  18.4 KB
    __shared__ __align__(16) unsigned short Vl[2][256][LPK];   // [buf][o][i]   73.7 KB
    __shared__ __align__(16) unsigned short St[128][LPK];      // [j][i]        18.4 KB

    int j0   = blockIdx.x * 128;
    int b    = blockIdx.y;
    int tid  = threadIdx.x;
    int lane = tid & 63;
    int w    = tid >> 6;
    int col  = lane & 15;
    int quad = lane >> 4;

    int wo  = w >> 1;    // phase-B o-group (0..3): 64 o
    int wj  = w & 1;     // phase-B j-group (0..1): 64 j
    int paj = w >> 1;    // phase-A jsub-pair (0..3): jsubs {2paj, 2paj+1}
    int pai = w & 1;     // phase-A isub-pair (0..1): isubs {2pai, 2pai+1}

    // iteration-invariant K fragments (2 jsubs x 2 k-chunks; B-op: n=j, k=ch)
    short8 bK[2][2];
#pragma unroll
    for (int jj = 0; jj < 2; ++jj) {
        int jrow = j0 + (paj * 2 + jj) * 16 + col;
#pragma unroll
        for (int ks = 0; ks < 2; ++ks)
            bK[jj][ks] = *(const short8*)(qk + ((size_t)b * NPIX + jrow) * 128 + 64 + ks * 32 + quad * 8);
    }

    f32x4 acc[4][4];   // [o-tile][j-tile]; D: col=o, rows=j
#pragma unroll
    for (int ot = 0; ot < 4; ++ot)
#pragma unroll
        for (int jt = 0; jt < 4; ++jt) acc[ot][jt] = (f32x4){0.f, 0.f, 0.f, 0.f};

    // prologue: stage tile 0 into buffer 0
    {
        int row = tid >> 3, q8 = tid & 7;
        uint4 q0 = *(const uint4*)(qk + ((size_t)b * NPIX + row) * 128 + q8 * 8);
        *(uint4*)&Qt[0][row][q8 * 8] = q0;
#pragma unroll
        for (int r = 0; r < 4; ++r) {
            int f = r * 512 + tid;
            uint4 v0 = *(const uint4*)(vp + ((size_t)b * CH + (f >> 3)) * NPIX + (f & 7) * 8);
            *(uint4*)&Vl[0][f >> 3][(f & 7) * 8] = v0;
        }
    }

    const float invN = 1.f / (float)NPIX;
    uint4 vr[4]; uint4 qr;

    for (int it = 0; it < NPIX / 64; ++it) {
        int p = it & 1;
        int more = (it + 1) < (NPIX / 64);
        int inext = (it + 1) * 64;

        // T14: issue next tile's global loads now; they land in regs during compute
        if (more) {
            int row = tid >> 3, q8 = tid & 7;
            qr = *(const uint4*)(qk + ((size_t)b * NPIX + inext + row) * 128 + q8 * 8);
#pragma unroll
            for (int r = 0; r < 4; ++r) {
                int f = r * 512 + tid;
                vr[r] = *(const uint4*)(vp + ((size_t)b * CH + (f >> 3)) * NPIX + inext + (f & 7) * 8);
            }
        }

        __syncthreads();   // buf[p] staged writes visible; St safe to overwrite

        // ---- phase A: S[64i x 128j] = Q.K^T, elu/N -> St[j][i] bf16 ----
#pragma unroll
        for (int ii = 0; ii < 2; ++ii) {
            int isub = pai * 2 + ii;
            short8 a0 = *(const short8*)&Qt[p][isub * 16 + col][quad * 8];
            short8 a1 = *(const short8*)&Qt[p][isub * 16 + col][32 + quad * 8];
#pragma unroll
            for (int jj = 0; jj < 2; ++jj) {
                f32x4 s = (f32x4){0.f, 0.f, 0.f, 0.f};
                s = MFMA16x16(a0, bK[jj][0], s);
                s = MFMA16x16(a1, bK[jj][1], s);
                unsigned int pk2[2];
#pragma unroll
                for (int pp = 0; pp < 2; ++pp) {
                    float e0 = s[pp * 2 + 0];
                    float e1 = s[pp * 2 + 1];
                    float g0 = __expf(e0) - 1.f;
                    float g1 = __expf(e1) - 1.f;
                    e0 = (e0 > 0.f) ? e0 : g0;
                    e1 = (e1 > 0.f) ? e1 : g1;
                    e0 *= invN;
                    e1 *= invN;
                    unsigned int rpk;
                    asm("v_cvt_pk_bf16_f32 %0, %1, %2" : "=v"(rpk) : "v"(e0), "v"(e1));
                    pk2[pp] = rpk;
                }
                // D of phase A: col=j, rows=4 consecutive i -> St[j][i] uint2
                *(uint2*)&St[(paj * 2 + jj) * 16 + col][isub * 16 + quad * 4] = *(uint2*)pk2;
            }
        }
        __syncthreads();   // St ready for all waves

        // ---- phase B: acc[ot][jt] += S(A: m=j,k=i) x V(B: n=o,k=i) ----
#pragma unroll
        for (int ks = 0; ks < 2; ++ks) {
            short8 sb[4];
#pragma unroll
            for (int jt = 0; jt < 4; ++jt)
                sb[jt] = *(const short8*)&St[wj * 64 + jt * 16 + col][ks * 32 + quad * 8];
#pragma unroll
            for (int ot = 0; ot < 4; ++ot) {
                short8 vb = *(const short8*)&Vl[p][wo * 64 + ot * 16 + col][ks * 32 + quad * 8];
                __builtin_amdgcn_s_setprio(1);
#pragma unroll
                for (int jt = 0; jt < 4; ++jt)
                    acc[ot][jt] = MFMA16x16(sb[jt], vb, acc[ot][jt]);
                __builtin_amdgcn_s_setprio(0);
            }
        }

        // write next tile into the other buffer (no barrier needed here:
        // readers of buf[p^1] are past the NEXT top-of-loop barrier)
        if (more) {
            int pn = p ^ 1;
            int row = tid >> 3, q8 = tid & 7;
            *(uint4*)&Qt[pn][row][q8 * 8] = qr;
#pragma unroll
            for (int r = 0; r < 4; ++r) {
                int f = r * 512 + tid;
                *(uint4*)&Vl[pn][f >> 3][(f & 7) * 8] = vr[r];
            }
        }
    }

    // epilogue: D col=o, rows=4 consecutive j -> float4 stores
#pragma unroll
    for (int ot = 0; ot < 4; ++ot) {
        int o = wo * 64 + ot * 16 + col;
        float bgv = bg[o];
#pragma unroll
        for (int jt = 0; jt < 4; ++jt) {
            int j = j0 + wj * 64 + jt * 16 + quad * 4;
            float4 st;
            st.x = acc[ot][jt][0] + bgv;
            st.y = acc[ot][jt][1] + bgv;
            st.z = acc[ot][jt][2] + bgv;
            st.w = acc[ot][jt][3] + bgv;
            *(float4*)&out[((size_t)b * CH + o) * NPIX + j] = st;
        }
    }
}

// ---------------------------------------------------------------------------
extern "C" void kernel_launch(void* const* d_in, const int* in_sizes, int n_in,
                              void* d_out, int out_size, void* d_ws, size_t ws_size,
                              hipStream_t stream) {
    const float* x  = (const float*)d_in[0];
    const float* wq = (const float*)d_in[1];
    const float* bq = (const float*)d_in[2];
    const float* wk = (const float*)d_in[3];
    const float* bk = (const float*)d_in[4];
    const float* wv = (const float*)d_in[5];
    const float* bv = (const float*)d_in[6];
    const float* wg = (const float*)d_in[7];
    const float* bg = (const float*)d_in[8];
    float* out = (float*)d_out;

    unsigned short* W_all = (unsigned short*)d_ws;
    float* bias_all = (float*)(W_all + 384 * 256);
    unsigned short* xt = (unsigned short*)(bias_all + 384);
    unsigned short* qk = xt + (size_t)BATCH * NPIX * CH;
    unsigned short* vp = qk + (size_t)BATCH * NPIX * 128;

    prep_kernel<<<dim3(384), dim3(256), 0, stream>>>(wq, bq, wk, bk, wv, bv, wg, W_all, bias_all);
    xpose_kernel<<<dim3(NPIX / 64, CH / 64, BATCH), dim3(256), 0, stream>>>(x, xt);
    qkv_mfma<<<dim3(NPIX / 64, BATCH), dim3(256), 0, stream>>>(xt, W_all, bias_all, qk, vp);
    attn_v5<<<dim3(NPIX / 128, BATCH), dim3(512), 0, stream>>>(qk, vp, bg, out);
}

// Round 2
// 266.027 us; speedup vs baseline: 1.1483x; 1.1483x over previous
//
#include <hip/hip_runtime.h>
#include <math.h>

#define BATCH 8
#define CH    256
#define NPIX  4096
#define CKDIM 64

typedef __attribute__((ext_vector_type(8))) short short8;   // 8 bf16 (4 VGPRs)
typedef __attribute__((ext_vector_type(4))) float f32x4;    // MFMA accumulator

#define MFMA16x16(a, b, c) __builtin_amdgcn_mfma_f32_16x16x32_bf16((a), (b), (c), 0, 0, 0)

__device__ __forceinline__ unsigned short f2bf(float f) {
    union { float f; unsigned int u; } v; v.f = f;
    unsigned int u = v.u;
    u += 0x7fffu + ((u >> 16) & 1u);      // round-to-nearest-even
    return (unsigned short)(u >> 16);
}

// ---------------------------------------------------------------------------
// Kernel P: build W_all[384][256] bf16 (rows: 0-63 wq, 64-127 wk, 128-383 wg@wv)
// and bias_all[384] fp32. grid 384 x 256 threads.
// ---------------------------------------------------------------------------
__global__ void prep_kernel(const float* __restrict__ wq, const float* __restrict__ bq,
                            const float* __restrict__ wk, const float* __restrict__ bk,
                            const float* __restrict__ wv, const float* __restrict__ bv,
                            const float* __restrict__ wg,
                            unsigned short* __restrict__ W_all, float* __restrict__ bias_all) {
    int o = blockIdx.x;
    int c = threadIdx.x;
    if (o < 64) {
        W_all[o * CH + c] = f2bf(wq[o * CH + c]);
        if (c == 0) bias_all[o] = bq[o];
    } else if (o < 128) {
        int oo = o - 64;
        W_all[o * CH + c] = f2bf(wk[oo * CH + c]);
        if (c == 0) bias_all[o] = bk[oo];
    } else {
        int oo = o - 128;
        float acc = 0.f;
        for (int m = 0; m < CH; ++m)
            acc += wg[oo * CH + m] * wv[m * CH + c];
        W_all[o * CH + c] = f2bf(acc);
        if (c == 0) {
            float b = 0.f;
            for (int m = 0; m < CH; ++m) b += wg[oo * CH + m] * bv[m];
            bias_all[o] = b;
        }
    }
}

// ---------------------------------------------------------------------------
// Kernel T: transpose+convert x[b][c][n] fp32 -> xt[b][n][c] bf16.
// 64x64 tiles, 256 threads. LDS stride 65 (<=2-way banks). grid (64, 4, 8).
// ---------------------------------------------------------------------------
__global__ void xpose_kernel(const float* __restrict__ x, unsigned short* __restrict__ xt) {
    __shared__ float Tl[64][65];   // [n][c]
    int n0 = blockIdx.x * 64;
    int c0 = blockIdx.y * 64;
    int b  = blockIdx.z;
    int tid = threadIdx.x;

#pragma unroll
    for (int r = 0; r < 4; ++r) {
        int f  = r * 256 + tid;
        int c  = f >> 4;
        int n4 = f & 15;
        float4 v = *(const float4*)(x + ((size_t)b * CH + c0 + c) * NPIX + n0 + n4 * 4);
        Tl[n4 * 4 + 0][c] = v.x;
        Tl[n4 * 4 + 1][c] = v.y;
        Tl[n4 * 4 + 2][c] = v.z;
        Tl[n4 * 4 + 3][c] = v.w;
    }
    __syncthreads();
#pragma unroll
    for (int r = 0; r < 2; ++r) {
        int f    = r * 256 + tid;
        int nrow = f >> 3;
        int c8   = f & 7;
        unsigned int pk[4];
#pragma unroll
        for (int p = 0; p < 4; ++p) {
            unsigned int lo = f2bf(Tl[nrow][c8 * 8 + p * 2 + 0]);
            unsigned int hi = f2bf(Tl[nrow][c8 * 8 + p * 2 + 1]);
            pk[p] = lo | (hi << 16);
        }
        *(uint4*)(xt + ((size_t)b * NPIX + n0 + nrow) * CH + c0 + c8 * 8) = *(uint4*)pk;
    }
}

// ---------------------------------------------------------------------------
// Kernel G: qkv GEMM. Stage 64n x 256ch xt tile in LDS once; loop 6 o-groups.
// y[o][n] = sum_c W_all[o][c] xt[n][c] + bias. o<128 -> qk[b][n][128];
// o>=128 -> vp[b][o-128][n]. grid (64, 8), 256 threads (4 waves).
// ---------------------------------------------------------------------------
__global__ void qkv_mfma(const unsigned short* __restrict__ xt,
                         const unsigned short* __restrict__ W_all,
                         const float* __restrict__ bias_all,
                         unsigned short* __restrict__ qk, unsigned short* __restrict__ vp) {
    __shared__ __align__(16) unsigned short Xl[64][264];   // 33 KB, stride 264 (~conflict-min)

    int n0   = blockIdx.x * 64;
    int b    = blockIdx.y;
    int tid  = threadIdx.x;
    int lane = tid & 63;
    int w    = tid >> 6;
    int col  = lane & 15;
    int quad = lane >> 4;

    // stage xt tile: 64 rows x 256 ch (8 uint4/thread, coalesced)
#pragma unroll
    for (int r = 0; r < 8; ++r) {
        int f   = r * 256 + tid;
        int row = f >> 5;            // 32 uint4 per row
        int c8  = f & 31;
        *(uint4*)&Xl[row][c8 * 8] = *(const uint4*)(xt + ((size_t)b * NPIX + n0 + row) * CH + c8 * 8);
    }
    __syncthreads();

#pragma unroll
    for (int og = 0; og < 6; ++og) {
        int o0 = og * 64;
        const unsigned short* Arow = W_all + (size_t)(o0 + w * 16 + col) * CH + quad * 8;

        f32x4 acc[4];
#pragma unroll
        for (int t = 0; t < 4; ++t) acc[t] = (f32x4){0.f, 0.f, 0.f, 0.f};

#pragma unroll
        for (int kc = 0; kc < 8; ++kc) {
            short8 a = *(const short8*)(Arow + kc * 32);   // L2-hot (196 KB total W)
#pragma unroll
            for (int nt = 0; nt < 4; ++nt) {
                short8 bb = *(const short8*)&Xl[nt * 16 + col][kc * 32 + quad * 8];
                acc[nt] = MFMA16x16(a, bb, acc[nt]);
            }
        }

        float4 bias = *(const float4*)(bias_all + o0 + w * 16 + quad * 4);
        float bs[4] = {bias.x, bias.y, bias.z, bias.w};

        if (og < 2) {
            // q/k: transposed store qk[b][n][o] (uint2 per tile)
#pragma unroll
            for (int nt = 0; nt < 4; ++nt) {
                int n = n0 + nt * 16 + col;
                unsigned int pk[2];
#pragma unroll
                for (int p = 0; p < 2; ++p) {
                    unsigned int lo = f2bf(acc[nt][p * 2 + 0] + bs[p * 2 + 0]);
                    unsigned int hi = f2bf(acc[nt][p * 2 + 1] + bs[p * 2 + 1]);
                    pk[p] = lo | (hi << 16);
                }
                *(uint2*)(qk + ((size_t)b * NPIX + n) * 128 + o0 + w * 16 + quad * 4) = *(uint2*)pk;
            }
        } else {
#pragma unroll
            for (int nt = 0; nt < 4; ++nt) {
                int n = n0 + nt * 16 + col;
#pragma unroll
                for (int r = 0; r < 4; ++r) {
                    int oo = o0 - 128 + w * 16 + quad * 4 + r;
                    vp[((size_t)b * CH + oo) * NPIX + n] = f2bf(acc[nt][r] + bs[r]);
                }
            }
        }
    }
}

// ---------------------------------------------------------------------------
// Kernel A v6: v4 shape (j-tile 64, 8 waves, 2 blocks/CU) minus V-LDS staging.
//  - V fragments read DIRECT from global (zero intra-block reuse -> LDS staging
//    was pure pass-through: -64 KB/block-iter LDS traffic). Prefetched one full
//    iteration ahead into regs (latency hidden under whole iteration).
//  - Q staged via reg prefetch + ds_write at top: 2 barriers/iter (was 3).
//  - LDS 18.4 KB (Qt+St only). 2 blocks/CU via grid 512; VGPR capped 128.
//  - XCD swizzle: lin&7 = batch -> each XCD serves ONE batch (Q+K+V=3MB < 4MB L2).
// Hazards: Qt/St write-after-read safe because lgkmcnt-before-MFMA completes all
// LDS reads before their wave reaches the next barrier.
// ---------------------------------------------------------------------------
#define LPK 72
__global__ __launch_bounds__(512, 4)
void attn_v6(const unsigned short* __restrict__ qk,   // [B][N][128]: q=0..63, k=64..127
             const unsigned short* __restrict__ vp,   // [B][256][N]
             const float* __restrict__ bg, float* __restrict__ out) {
    __shared__ __align__(16) unsigned short Qt[64][LPK];   // [i][ch]  9.2 KB
    __shared__ __align__(16) unsigned short St[64][LPK];   // [j][i]   9.2 KB

    int lin  = blockIdx.y * gridDim.x + blockIdx.x;
    int b    = lin & 7;                 // XCD-swizzle: one batch per XCD
    int j0   = (lin >> 3) * 64;
    int tid  = threadIdx.x;
    int lane = tid & 63;
    int w    = tid >> 6;
    int col  = lane & 15;
    int quad = lane >> 4;

    int tjA = w & 3;              // phase-A j-tile (this wave's K column block)
    int tiP = (w >> 2) * 2;       // phase-A i-tile pair

    // iteration-invariant K fragments (global, once; B-operand: n=j, k=ch)
    short8 bK[2];
#pragma unroll
    for (int ks = 0; ks < 2; ++ks)
        bK[ks] = *(const short8*)(qk + ((size_t)b * NPIX + j0 + tjA * 16 + col) * 128 + 64 + ks * 32 + quad * 8);

    f32x4 acc[2][4];   // [o-tile][j-tile]; D: col=o, rows=j
#pragma unroll
    for (int ot = 0; ot < 2; ++ot)
#pragma unroll
        for (int tj = 0; tj < 4; ++tj) acc[ot][tj] = (f32x4){0.f, 0.f, 0.f, 0.f};

    // per-thread staging coords
    int qrow = tid >> 3, q8 = tid & 7;
    const unsigned short* Qsrc = qk + ((size_t)b * NPIX + qrow) * 128 + q8 * 8;
    const unsigned short* Vsrc[2];
#pragma unroll
    for (int ot = 0; ot < 2; ++ot)
        Vsrc[ot] = vp + ((size_t)b * CH + (w * 2 + ot) * 16 + col) * NPIX + quad * 8;

    // prologue: prefetch i-tile 0 into regs
    uint4 qr = *(const uint4*)Qsrc;
    short8 vb[2][2];
#pragma unroll
    for (int ot = 0; ot < 2; ++ot)
#pragma unroll
        for (int ks = 0; ks < 2; ++ks)
            vb[ot][ks] = *(const short8*)(Vsrc[ot] + ks * 32);

    const float invN = 1.f / (float)NPIX;

    for (int i0 = 0; i0 < NPIX; i0 += 64) {
        // stage Qt from prefetched regs (safe: everyone passed prev bar2)
        *(uint4*)&Qt[qrow][q8 * 8] = qr;

        // prefetch NEXT i-tile into regs (wraps to 0 on last iter -- harmless)
        int inext = (i0 + 64) & (NPIX - 1);
        uint4 qr_n = *(const uint4*)(Qsrc + (size_t)inext * 128);
        short8 vb_n[2][2];
#pragma unroll
        for (int ot = 0; ot < 2; ++ot)
#pragma unroll
            for (int ks = 0; ks < 2; ++ks)
                vb_n[ot][ks] = *(const short8*)(Vsrc[ot] + inext + ks * 32);

        __syncthreads();   // bar1: Qt visible; prev phase-B St reads complete

        // ---- phase A: S[64x64] = Q.K^T, elu/N -> St[j][i] bf16 ----
#pragma unroll
        for (int t = 0; t < 2; ++t) {
            int ti = tiP + t;
            short8 a0 = *(const short8*)&Qt[ti * 16 + col][quad * 8];
            short8 a1 = *(const short8*)&Qt[ti * 16 + col][32 + quad * 8];
            f32x4 s = (f32x4){0.f, 0.f, 0.f, 0.f};
            s = MFMA16x16(a0, bK[0], s);
            s = MFMA16x16(a1, bK[1], s);
            unsigned int pk2[2];
#pragma unroll
            for (int pp = 0; pp < 2; ++pp) {
                float e0 = s[pp * 2 + 0];
                float e1 = s[pp * 2 + 1];
                float g0 = __expf(e0) - 1.f;
                float g1 = __expf(e1) - 1.f;
                e0 = (e0 > 0.f) ? e0 : g0;
                e1 = (e1 > 0.f) ? e1 : g1;
                e0 *= invN;
                e1 *= invN;
                unsigned int rpk;
                asm("v_cvt_pk_bf16_f32 %0, %1, %2" : "=v"(rpk) : "v"(e0), "v"(e1));
                pk2[pp] = rpk;
            }
            // D of phase A: col=j, rows=4 consecutive i -> St[j][i] uint2
            *(uint2*)&St[tjA * 16 + col][ti * 16 + quad * 4] = *(uint2*)pk2;
        }
        __syncthreads();   // bar2: St ready for all waves

        // ---- phase B: acc[ot][tj] += S(A: m=j,k=i) x V(B-regs: n=o,k=i) ----
#pragma unroll
        for (int ks = 0; ks < 2; ++ks) {
            short8 sb[4];
#pragma unroll
            for (int tj = 0; tj < 4; ++tj)
                sb[tj] = *(const short8*)&St[tj * 16 + col][ks * 32 + quad * 8];
            __builtin_amdgcn_s_setprio(1);
#pragma unroll
            for (int ot = 0; ot < 2; ++ot)
#pragma unroll
                for (int tj = 0; tj < 4; ++tj)
                    acc[ot][tj] = MFMA16x16(sb[tj], vb[ot][ks], acc[ot][tj]);
            __builtin_amdgcn_s_setprio(0);
        }

        // rotate prefetch regs
        qr = qr_n;
#pragma unroll
        for (int ot = 0; ot < 2; ++ot)
#pragma unroll
            for (int ks = 0; ks < 2; ++ks)
                vb[ot][ks] = vb_n[ot][ks];
    }

    // epilogue: D col=o, rows=4 consecutive j -> float4 stores
#pragma unroll
    for (int ot = 0; ot < 2; ++ot) {
        int o = (w * 2 + ot) * 16 + col;
        float bgv = bg[o];
#pragma unroll
        for (int tj = 0; tj < 4; ++tj) {
            int j = j0 + tj * 16 + quad * 4;
            float4 st;
            st.x = acc[ot][tj][0] + bgv;
            st.y = acc[ot][tj][1] + bgv;
            st.z = acc[ot][tj][2] + bgv;
            st.w = acc[ot][tj][3] + bgv;
            *(float4*)&out[((size_t)b * CH + o) * NPIX + j] = st;
        }
    }
}

// ---------------------------------------------------------------------------
extern "C" void kernel_launch(void* const* d_in, const int* in_sizes, int n_in,
                              void* d_out, int out_size, void* d_ws, size_t ws_size,
                              hipStream_t stream) {
    const float* x  = (const float*)d_in[0];
    const float* wq = (const float*)d_in[1];
    const float* bq = (const float*)d_in[2];
    const float* wk = (const float*)d_in[3];
    const float* bk = (const float*)d_in[4];
    const float* wv = (const float*)d_in[5];
    const float* bv = (const float*)d_in[6];
    const float* wg = (const float*)d_in[7];
    const float* bg = (const float*)d_in[8];
    float* out = (float*)d_out;

    unsigned short* W_all = (unsigned short*)d_ws;
    float* bias_all = (float*)(W_all + 384 * 256);
    unsigned short* xt = (unsigned short*)(bias_all + 384);
    unsigned short* qk = xt + (size_t)BATCH * NPIX * CH;
    unsigned short* vp = qk + (size_t)BATCH * NPIX * 128;

    prep_kernel<<<dim3(384), dim3(256), 0, stream>>>(wq, bq, wk, bk, wv, bv, wg, W_all, bias_all);
    xpose_kernel<<<dim3(NPIX / 64, CH / 64, BATCH), dim3(256), 0, stream>>>(x, xt);
    qkv_mfma<<<dim3(NPIX / 64, BATCH), dim3(256), 0, stream>>>(xt, W_all, bias_all, qk, vp);
    attn_v6<<<dim3(NPIX / 64, BATCH), dim3(512), 0, stream>>>(qk, vp, bg, out);
}